// Round 3
// baseline (293.116 us; speedup 1.0000x reference)
//
#include <hip/hip_runtime.h>

#define BB 256
#define NP 12
#define TT 20
#define DD 512
#define EPS_A 1e-6f
#define EPS_BN 1e-5f
#define THR2 (150.0f * 150.0f)
#define APITCH 520            // ushorts per A-tile row (1040 B)
#define NSLICE 2432u          // float4 of non-slice data per (b,n) group (19 rows)
#define TOTALC 7471104u       // 3072 groups * 2432  (FIXED: was 7469056)
#define CSPLIT 2990080u       // compute kernel copies [0,CSPLIT), copyprep [CSPLIT,TOTALC)
#define NCOPY1 2016           // copy blocks in copyprep
#define NCOPY2 256            // copy blocks in compute kernel

typedef __attribute__((ext_vector_type(8))) short shortx8;
typedef __attribute__((ext_vector_type(4))) float floatx4;

static __device__ __forceinline__ ushort f2bf(float f) {
    unsigned x = __float_as_uint(f);
    return (ushort)((x + 0x7fffu + ((x >> 16) & 1u)) >> 16);  // RNE
}

// Copy non-slice float4 range [lo,hi) of the *linearized non-slice index space*.
// Linear index i maps to memory index i + (i/2432)*128 (skips the 128-float4 slice
// row of each 2560-float4 group). Strip of 8 consecutive float4 per thread per iter:
// alignment (lo%8==0, 2432%8==0) guarantees a strip never crosses a group boundary.
static __device__ __forceinline__ void copy_span(uint lo, uint hi, uint tid, uint cb,
                                                 uint ncb, uint tpb,
                                                 const float4* __restrict__ src,
                                                 float4* __restrict__ dst) {
    uint step = ncb * tpb * 8u;
    for (uint i0 = lo + (cb * tpb + tid) * 8u; i0 < hi; i0 += step) {
        uint g = i0 / NSLICE;
        uint idx = i0 + g * 128u;
        float4 v0 = src[idx + 0], v1 = src[idx + 1], v2 = src[idx + 2], v3 = src[idx + 3];
        float4 v4 = src[idx + 4], v5 = src[idx + 5], v6 = src[idx + 6], v7 = src[idx + 7];
        dst[idx + 0] = v0; dst[idx + 1] = v1; dst[idx + 2] = v2; dst[idx + 3] = v3;
        dst[idx + 4] = v4; dst[idx + 5] = v5; dst[idx + 6] = v6; dst[idx + 7] = v7;
    }
}

// ---------------------------------------------------------------------------
// copyprep: [0,64) cast W1,W2 -> bf16 ; [64] BN vecs ; [65,65+NCOPY1) copy.
// Zero LDS, low VGPR -> full occupancy for the copy blocks.
// ---------------------------------------------------------------------------
__global__ __launch_bounds__(256) void k_copyprep(
    const float* __restrict__ W1, const float* __restrict__ W2,
    const float* __restrict__ b1, const float* __restrict__ g1,
    const float* __restrict__ beta1, const float* __restrict__ m1, const float* __restrict__ v1,
    const float* __restrict__ b2, const float* __restrict__ g2,
    const float* __restrict__ beta2, const float* __restrict__ m2, const float* __restrict__ v2,
    float* __restrict__ s1, float* __restrict__ t1, float* __restrict__ s2, float* __restrict__ t2,
    ushort* __restrict__ wb1, ushort* __restrict__ wb2,
    const float4* __restrict__ csrc, float4* __restrict__ cdst) {
    int bid = blockIdx.x, t = threadIdx.x;
    if (bid < 64) {  // 131072 float4 total (W1 then W2)
        int idx = bid * 256 + t;
        #pragma unroll 2
        for (int i = idx; i < 131072; i += 16384) {
            float4 f = (i < 65536) ? ((const float4*)W1)[i] : ((const float4*)W2)[i - 65536];
            ushort4 u;
            u.x = f2bf(f.x); u.y = f2bf(f.y); u.z = f2bf(f.z); u.w = f2bf(f.w);
            if (i < 65536) *(ushort4*)(wb1 + (long)i * 4) = u;
            else           *(ushort4*)(wb2 + (long)(i - 65536) * 4) = u;
        }
    } else if (bid == 64) {
        for (int d = t; d < DD; d += 256) {
            float sa = g1[d] * rsqrtf(v1[d] + EPS_BN);
            s1[d] = sa; t1[d] = (b1[d] - m1[d]) * sa + beta1[d];
            float sb = g2[d] * rsqrtf(v2[d] + EPS_BN);
            s2[d] = sb; t2[d] = (b2[d] - m2[d]) * sb + beta2[d];
        }
    } else {
        copy_span(CSPLIT, TOTALC, t, bid - 65, NCOPY1, 256, csrc, cdst);
    }
}

// ---------------------------------------------------------------------------
// Per-batch GEMM, 8 waves: wave owns 64 output cols (4 n-tiles). M=12 in one
// 16-row tile. A from LDS, B (bf16 W) streamed from global (L2/L3-hot).
// ---------------------------------------------------------------------------
template <int LAYER>
static __device__ __forceinline__ void gemm8w(
    int wave, int lane, int b,
    const ushort (*__restrict__ xgl)[APITCH], float (*__restrict__ y1l)[DD],
    const ushort* __restrict__ wb, const float* __restrict__ sv, const float* __restrict__ tv,
    float* __restrict__ outp) {
    int mrow = lane & 15, quad = lane >> 4;
    floatx4 acc[4];
    #pragma unroll
    for (int nt = 0; nt < 4; nt++) acc[nt] = (floatx4){0.f, 0.f, 0.f, 0.f};

    const ushort* wbase = wb + ((long)(wave * 64 + mrow)) * DD + quad * 8;
    #pragma unroll 4
    for (int kc = 0; kc < DD; kc += 32) {
        shortx8 af = *(const shortx8*)&xgl[mrow][kc + quad * 8];
        #pragma unroll
        for (int nt = 0; nt < 4; nt++) {
            shortx8 bf = *(const shortx8*)(wbase + nt * 16 * DD + kc);
            acc[nt] = __builtin_amdgcn_mfma_f32_16x16x32_bf16(af, bf, acc[nt], 0, 0, 0);
        }
    }

    #pragma unroll
    for (int nt = 0; nt < 4; nt++) {
        int d = wave * 64 + nt * 16 + mrow;
        float s = sv[d], tt = tv[d];
        #pragma unroll
        for (int v = 0; v < 4; v++) {
            int m = quad * 4 + v;
            float val = fmaxf(acc[nt][v] * s + tt, 0.f);
            if (m < NP) {
                if (LAYER == 1) y1l[m][d] = val;
                else outp[((long)(b * NP + m) * TT + (TT - 1)) * DD + d] = val;
            }
        }
    }
}

// ---------------------------------------------------------------------------
// compute: blocks [0,256) full per-batch STGCN chain; blocks [256,512) carry
// the front 40% of the copy so compute latency hides under streaming traffic.
// ---------------------------------------------------------------------------
__global__ __launch_bounds__(512, 4) void k_compute(
    const float* __restrict__ pf, const float* __restrict__ bboxes,
    const ushort* __restrict__ wb1, const ushort* __restrict__ wb2,
    const float* __restrict__ s1, const float* __restrict__ t1,
    const float* __restrict__ s2, const float* __restrict__ t2,
    float* __restrict__ out,
    const float4* __restrict__ csrc, float4* __restrict__ cdst) {
    __shared__ float cx[NP], cy[NP], Ash[NP][NP], rinv[NP], at[NP][NP];
    __shared__ __align__(16) ushort xgl[16][APITCH];  // bf16 A-tile (rows 12..15 zero)
    __shared__ float y1l[NP][DD];                     // fp32 layer-1 output

    int bid = blockIdx.x, t = threadIdx.x;
    if (bid >= BB) {
        copy_span(0u, CSPLIT, t, bid - BB, NCOPY2, 512, csrc, cdst);
        return;
    }

    int b = bid;
    int lane = t & 63, wave = t >> 6;

    // ---- adjacency ----
    if (t < NP) {
        const float* p = bboxes + (b * NP + t) * 4;
        cx[t] = p[0] + 0.5f * p[2];
        cy[t] = p[1] + 0.5f * p[3];
    }
    // zero pad rows 12..15 of xgl (MFMA reads them; must be 0)
    {
        uint* xz = (uint*)&xgl[NP][0];
        for (int i = t; i < 4 * APITCH / 2; i += 512) xz[i] = 0;
    }
    __syncthreads();
    if (t < NP * NP) {
        int n = t / NP, k = t % NP;
        float dx = cx[n] - cx[k], dy = cy[n] - cy[k];
        Ash[n][k] = (dx * dx + dy * dy < THR2) ? 1.f : 0.f;
    }
    __syncthreads();
    if (t < NP) {
        float s = 0.f;
        #pragma unroll
        for (int k = 0; k < NP; k++) s += Ash[t][k];
        rinv[t] = 1.f / (s + EPS_A);
    }
    __syncthreads();
    if (t < NP * NP) {
        int j = t / NP, n = t % NP;
        at[j][n] = Ash[n][j] * rinv[n];
    }
    __syncthreads();

    // ---- mix1: pf last slice -> xgl (bf16) ----
    for (int c = t; c < DD; c += 512) {
        float xv[NP];
        #pragma unroll
        for (int n = 0; n < NP; n++)
            xv[n] = pf[((long)((b * NP + n) * TT + TT - 1)) * DD + c];
        #pragma unroll
        for (int j = 0; j < NP; j++) {
            float a = 0.f;
            #pragma unroll
            for (int n = 0; n < NP; n++) a += at[j][n] * xv[n];
            xgl[j][c] = f2bf(a);
        }
    }
    __syncthreads();

    // ---- layer 1 GEMM + BN + relu -> y1l ----
    gemm8w<1>(wave, lane, b, xgl, y1l, wb1, s1, t1, nullptr);
    __syncthreads();  // y1l written; xgl reads done

    // ---- mix2: y1l -> xgl (bf16) ----
    for (int c = t; c < DD; c += 512) {
        float xv[NP];
        #pragma unroll
        for (int n = 0; n < NP; n++) xv[n] = y1l[n][c];
        #pragma unroll
        for (int j = 0; j < NP; j++) {
            float a = 0.f;
            #pragma unroll
            for (int n = 0; n < NP; n++) a += at[j][n] * xv[n];
            xgl[j][c] = f2bf(a);
        }
    }
    __syncthreads();

    // ---- layer 2 GEMM + BN + relu -> out slice rows ----
    gemm8w<2>(wave, lane, b, xgl, y1l, wb2, s2, t2, out);
}

// ---------------------------------------------------------------------------
extern "C" void kernel_launch(void* const* d_in, const int* in_sizes, int n_in,
                              void* d_out, int out_size, void* d_ws, size_t ws_size,
                              hipStream_t stream) {
    const float* pf = (const float*)d_in[0];
    const float* bboxes = (const float*)d_in[1];
    const float* W1 = (const float*)d_in[2];
    const float* b1 = (const float*)d_in[3];
    const float* g1 = (const float*)d_in[4];
    const float* beta1 = (const float*)d_in[5];
    const float* m1 = (const float*)d_in[6];
    const float* v1 = (const float*)d_in[7];
    const float* W2 = (const float*)d_in[8];
    const float* b2 = (const float*)d_in[9];
    const float* g2 = (const float*)d_in[10];
    const float* beta2 = (const float*)d_in[11];
    const float* m2 = (const float*)d_in[12];
    const float* v2 = (const float*)d_in[13];
    float* out = (float*)d_out;

    float* ws = (float*)d_ws;
    float* s1 = ws;
    float* t1v = ws + 512;
    float* s2 = ws + 1024;
    float* t2v = ws + 1536;
    ushort* wb1 = (ushort*)(ws + 2048);   // 262144 ushorts
    ushort* wb2 = wb1 + 262144;           // 262144 ushorts

    const float4* csrc = (const float4*)pf;
    float4* cdst = (float4*)out;

    k_copyprep<<<65 + NCOPY1, 256, 0, stream>>>(W1, W2, b1, g1, beta1, m1, v1,
                                                b2, g2, beta2, m2, v2,
                                                s1, t1v, s2, t2v, wb1, wb2, csrc, cdst);
    k_compute<<<BB + NCOPY2, 512, 0, stream>>>(pf, bboxes, wb1, wb2,
                                               s1, t1v, s2, t2v, out, csrc, cdst);
}

// Round 4
// 274.149 us; speedup vs baseline: 1.0692x; 1.0692x over previous
//
#include <hip/hip_runtime.h>

#define BB 256
#define NP 12
#define TT 20
#define DD 512
#define EPS_A 1e-6f
#define EPS_BN 1e-5f
#define THR2 (150.0f * 150.0f)
#define APITCH 520            // ushorts per A-tile row (1040 B)
#define CTOTAL 7864320L       // pf/out size in float4 units (256*12*20*512/4)
#define K2LO   5898240L       // K1 copies [0,K2LO), K2 copies [K2LO,CTOTAL)
#define NCPY1 2048            // copy blocks in K1
#define NCPY2 1024            // copy blocks in K2

typedef __attribute__((ext_vector_type(8))) short shortx8;
typedef __attribute__((ext_vector_type(4))) float floatx4;

static __device__ __forceinline__ ushort f2bf(float f) {
    unsigned x = __float_as_uint(f);
    return (ushort)((x + 0x7fffu + ((x >> 16) & 1u)) >> 16);  // RNE
}

// Coalesced grid-stride float4 copy of [lo,hi): lane i -> float4 i (1 KB/wave/instr).
// Skips t==19 rows everywhere; those are written by K2's compute blocks.
static __device__ __forceinline__ void copy_body(int cb, int ncb, int tpb, long lo, long hi,
                                                 const float4* __restrict__ src,
                                                 float4* __restrict__ dst) {
    long stride = (long)ncb * tpb;
    for (long g = lo + (long)cb * tpb + threadIdx.x; g < hi; g += stride) {
        int row = (int)(g >> 7);           // 128 float4 per 512-float row
        if (row % TT == TT - 1) continue;  // slice rows: computed, not copied
        dst[g] = src[g];
    }
}

// ---------------------------------------------------------------------------
// K1: [0,128) cast W1,W2 -> bf16 ; [128] BN vecs ; [129,129+NCPY1) copy 75%.
// Zero LDS, low VGPR -> 32 waves/CU for the copy blocks.
// ---------------------------------------------------------------------------
__global__ __launch_bounds__(256) void k_copyprep(
    const float* __restrict__ W1, const float* __restrict__ W2,
    const float* __restrict__ b1, const float* __restrict__ g1,
    const float* __restrict__ beta1, const float* __restrict__ m1, const float* __restrict__ v1,
    const float* __restrict__ b2, const float* __restrict__ g2,
    const float* __restrict__ beta2, const float* __restrict__ m2, const float* __restrict__ v2,
    float* __restrict__ s1, float* __restrict__ t1, float* __restrict__ s2, float* __restrict__ t2,
    ushort* __restrict__ wb1, ushort* __restrict__ wb2,
    const float4* __restrict__ csrc, float4* __restrict__ cdst) {
    int bid = blockIdx.x, t = threadIdx.x;
    if (bid < 128) {  // 131072 float4 total (W1 then W2), 4 iters/thread
        int idx = bid * 256 + t;
        #pragma unroll
        for (int k = 0; k < 4; k++) {
            int i = idx + k * 32768;
            float4 f = (i < 65536) ? ((const float4*)W1)[i] : ((const float4*)W2)[i - 65536];
            ushort4 u;
            u.x = f2bf(f.x); u.y = f2bf(f.y); u.z = f2bf(f.z); u.w = f2bf(f.w);
            if (i < 65536) *(ushort4*)(wb1 + (long)i * 4) = u;
            else           *(ushort4*)(wb2 + (long)(i - 65536) * 4) = u;
        }
    } else if (bid == 128) {
        for (int d = t; d < DD; d += 256) {
            float sa = g1[d] * rsqrtf(v1[d] + EPS_BN);
            s1[d] = sa; t1[d] = (b1[d] - m1[d]) * sa + beta1[d];
            float sb = g2[d] * rsqrtf(v2[d] + EPS_BN);
            s2[d] = sb; t2[d] = (b2[d] - m2[d]) * sb + beta2[d];
        }
    } else {
        copy_body(bid - 129, NCPY1, 256, 0L, K2LO, csrc, cdst);
    }
}

// ---------------------------------------------------------------------------
// Per-batch GEMM, 8 waves: wave owns 64 output cols (4 n-tiles). M=12 in one
// 16-row tile. A from LDS, B (bf16 W) streamed from global (L2/L3-hot).
// ---------------------------------------------------------------------------
template <int LAYER>
static __device__ __forceinline__ void gemm8w(
    int wave, int lane, int b,
    const ushort (*__restrict__ xgl)[APITCH], float (*__restrict__ y1l)[DD],
    const ushort* __restrict__ wb, const float* __restrict__ sv, const float* __restrict__ tv,
    float* __restrict__ outp) {
    int mrow = lane & 15, quad = lane >> 4;
    floatx4 acc[4];
    #pragma unroll
    for (int nt = 0; nt < 4; nt++) acc[nt] = (floatx4){0.f, 0.f, 0.f, 0.f};

    const ushort* wbase = wb + ((long)(wave * 64 + mrow)) * DD + quad * 8;
    #pragma unroll 4
    for (int kc = 0; kc < DD; kc += 32) {
        shortx8 af = *(const shortx8*)&xgl[mrow][kc + quad * 8];
        #pragma unroll
        for (int nt = 0; nt < 4; nt++) {
            shortx8 bf = *(const shortx8*)(wbase + nt * 16 * DD + kc);
            acc[nt] = __builtin_amdgcn_mfma_f32_16x16x32_bf16(af, bf, acc[nt], 0, 0, 0);
        }
    }

    #pragma unroll
    for (int nt = 0; nt < 4; nt++) {
        int d = wave * 64 + nt * 16 + mrow;
        float s = sv[d], tt = tv[d];
        #pragma unroll
        for (int v = 0; v < 4; v++) {
            int m = quad * 4 + v;
            float val = fmaxf(acc[nt][v] * s + tt, 0.f);
            if (m < NP) {
                if (LAYER == 1) y1l[m][d] = val;
                else outp[((long)(b * NP + m) * TT + (TT - 1)) * DD + d] = val;
            }
        }
    }
}

// ---------------------------------------------------------------------------
// K2: blocks [0,256) full per-batch STGCN chain; blocks [256,256+NCPY2)
// coalesced-copy the remaining 25% so compute latency hides under traffic.
// ---------------------------------------------------------------------------
__global__ __launch_bounds__(512, 4) void k_compute(
    const float* __restrict__ pf, const float* __restrict__ bboxes,
    const ushort* __restrict__ wb1, const ushort* __restrict__ wb2,
    const float* __restrict__ s1, const float* __restrict__ t1,
    const float* __restrict__ s2, const float* __restrict__ t2,
    float* __restrict__ out,
    const float4* __restrict__ csrc, float4* __restrict__ cdst) {
    __shared__ float cx[NP], cy[NP], Ash[NP][NP], rinv[NP], at[NP][NP];
    __shared__ __align__(16) ushort xgl[16][APITCH];  // bf16 A-tile (rows 12..15 zero)
    __shared__ float y1l[NP][DD];                     // fp32 layer-1 output

    int bid = blockIdx.x, t = threadIdx.x;
    if (bid >= BB) {
        copy_body(bid - BB, NCPY2, 512, K2LO, CTOTAL, csrc, cdst);
        return;
    }

    int b = bid;
    int lane = t & 63, wave = t >> 6;

    // ---- adjacency ----
    if (t < NP) {
        const float* p = bboxes + (b * NP + t) * 4;
        cx[t] = p[0] + 0.5f * p[2];
        cy[t] = p[1] + 0.5f * p[3];
    }
    // zero pad rows 12..15 of xgl (MFMA reads them; must be 0)
    {
        uint* xz = (uint*)&xgl[NP][0];
        for (int i = t; i < 4 * APITCH / 2; i += 512) xz[i] = 0;
    }
    __syncthreads();
    if (t < NP * NP) {
        int n = t / NP, k = t % NP;
        float dx = cx[n] - cx[k], dy = cy[n] - cy[k];
        Ash[n][k] = (dx * dx + dy * dy < THR2) ? 1.f : 0.f;
    }
    __syncthreads();
    if (t < NP) {
        float s = 0.f;
        #pragma unroll
        for (int k = 0; k < NP; k++) s += Ash[t][k];
        rinv[t] = 1.f / (s + EPS_A);
    }
    __syncthreads();
    if (t < NP * NP) {
        int j = t / NP, n = t % NP;
        at[j][n] = Ash[n][j] * rinv[n];
    }
    __syncthreads();

    // ---- mix1: pf last slice -> xgl (bf16) ----
    for (int c = t; c < DD; c += 512) {
        float xv[NP];
        #pragma unroll
        for (int n = 0; n < NP; n++)
            xv[n] = pf[((long)((b * NP + n) * TT + TT - 1)) * DD + c];
        #pragma unroll
        for (int j = 0; j < NP; j++) {
            float a = 0.f;
            #pragma unroll
            for (int n = 0; n < NP; n++) a += at[j][n] * xv[n];
            xgl[j][c] = f2bf(a);
        }
    }
    __syncthreads();

    // ---- layer 1 GEMM + BN + relu -> y1l ----
    gemm8w<1>(wave, lane, b, xgl, y1l, wb1, s1, t1, nullptr);
    __syncthreads();  // y1l written; xgl reads done

    // ---- mix2: y1l -> xgl (bf16) ----
    for (int c = t; c < DD; c += 512) {
        float xv[NP];
        #pragma unroll
        for (int n = 0; n < NP; n++) xv[n] = y1l[n][c];
        #pragma unroll
        for (int j = 0; j < NP; j++) {
            float a = 0.f;
            #pragma unroll
            for (int n = 0; n < NP; n++) a += at[j][n] * xv[n];
            xgl[j][c] = f2bf(a);
        }
    }
    __syncthreads();

    // ---- layer 2 GEMM + BN + relu -> out slice rows ----
    gemm8w<2>(wave, lane, b, xgl, y1l, wb2, s2, t2, out);
}

// ---------------------------------------------------------------------------
extern "C" void kernel_launch(void* const* d_in, const int* in_sizes, int n_in,
                              void* d_out, int out_size, void* d_ws, size_t ws_size,
                              hipStream_t stream) {
    const float* pf = (const float*)d_in[0];
    const float* bboxes = (const float*)d_in[1];
    const float* W1 = (const float*)d_in[2];
    const float* b1 = (const float*)d_in[3];
    const float* g1 = (const float*)d_in[4];
    const float* beta1 = (const float*)d_in[5];
    const float* m1 = (const float*)d_in[6];
    const float* v1 = (const float*)d_in[7];
    const float* W2 = (const float*)d_in[8];
    const float* b2 = (const float*)d_in[9];
    const float* g2 = (const float*)d_in[10];
    const float* beta2 = (const float*)d_in[11];
    const float* m2 = (const float*)d_in[12];
    const float* v2 = (const float*)d_in[13];
    float* out = (float*)d_out;

    float* ws = (float*)d_ws;
    float* s1 = ws;
    float* t1v = ws + 512;
    float* s2 = ws + 1024;
    float* t2v = ws + 1536;
    ushort* wb1 = (ushort*)(ws + 2048);   // 262144 ushorts
    ushort* wb2 = wb1 + 262144;           // 262144 ushorts

    const float4* csrc = (const float4*)pf;
    float4* cdst = (float4*)out;

    k_copyprep<<<129 + NCPY1, 256, 0, stream>>>(W1, W2, b1, g1, beta1, m1, v1,
                                                b2, g2, beta2, m2, v2,
                                                s1, t1v, s2, t2v, wb1, wb2, csrc, cdst);
    k_compute<<<BB + NCPY2, 512, 0, stream>>>(pf, bboxes, wb1, wb2,
                                              s1, t1v, s2, t2v, out, csrc, cdst);
}

// Round 5
// 266.235 us; speedup vs baseline: 1.1010x; 1.0297x over previous
//
#include <hip/hip_runtime.h>

#define BB 256
#define NP 12
#define TT 20
#define DD 512
#define EPS_A 1e-6f
#define EPS_BN 1e-5f
#define THR2 (150.0f * 150.0f)
#define APITCH 520            // ushorts per A-tile row (1040 B)
#define NCPY 1824             // copy blocks: 1824*8 waves = 14592 units of 4 rows = 58368 rows
#define NSROWS 58368          // non-slice rows (61440 total - 3072 slice rows)

typedef __attribute__((ext_vector_type(8))) short shortx8;
typedef __attribute__((ext_vector_type(4))) float floatx4;

static __device__ __forceinline__ ushort f2bf(float f) {
    unsigned x = __float_as_uint(f);
    return (ushort)((x + 0x7fffu + ((x >> 16) & 1u)) >> 16);  // RNE
}

// ---------------------------------------------------------------------------
// prep: [0,256) cast W1,W2 -> bf16 (1 f4 of each per thread) ; [256] BN vecs.
// Tiny (~4 us); the only work the compute chain depends on.
// ---------------------------------------------------------------------------
__global__ __launch_bounds__(256) void k_prep(
    const float* __restrict__ W1, const float* __restrict__ W2,
    const float* __restrict__ b1, const float* __restrict__ g1,
    const float* __restrict__ beta1, const float* __restrict__ m1, const float* __restrict__ v1,
    const float* __restrict__ b2, const float* __restrict__ g2,
    const float* __restrict__ beta2, const float* __restrict__ m2, const float* __restrict__ v2,
    float* __restrict__ s1, float* __restrict__ t1, float* __restrict__ s2, float* __restrict__ t2,
    ushort* __restrict__ wb1, ushort* __restrict__ wb2) {
    int bid = blockIdx.x, t = threadIdx.x;
    if (bid < 256) {  // 65536 float4 in each of W1, W2
        int i = bid * 256 + t;
        float4 f1 = ((const float4*)W1)[i];
        float4 f2 = ((const float4*)W2)[i];
        ushort4 u1, u2;
        u1.x = f2bf(f1.x); u1.y = f2bf(f1.y); u1.z = f2bf(f1.z); u1.w = f2bf(f1.w);
        u2.x = f2bf(f2.x); u2.y = f2bf(f2.y); u2.z = f2bf(f2.z); u2.w = f2bf(f2.w);
        *(ushort4*)(wb1 + (long)i * 4) = u1;
        *(ushort4*)(wb2 + (long)i * 4) = u2;
    } else {
        for (int d = t; d < DD; d += 256) {
            float sa = g1[d] * rsqrtf(v1[d] + EPS_BN);
            s1[d] = sa; t1[d] = (b1[d] - m1[d]) * sa + beta1[d];
            float sb = g2[d] * rsqrtf(v2[d] + EPS_BN);
            s2[d] = sb; t2[d] = (b2[d] - m2[d]) * sb + beta2[d];
        }
    }
}

// ---------------------------------------------------------------------------
// Per-batch GEMM, 8 waves: wave owns 64 output cols (4 n-tiles). M=12 in one
// 16-row tile. A from LDS, B (bf16 W) streamed from global (L2/L3-hot).
// ---------------------------------------------------------------------------
template <int LAYER>
static __device__ __forceinline__ void gemm8w(
    int wave, int lane, int b,
    const ushort (*__restrict__ xgl)[APITCH], float (*__restrict__ y1l)[DD],
    const ushort* __restrict__ wb, const float* __restrict__ sv, const float* __restrict__ tv,
    float* __restrict__ outp) {
    int mrow = lane & 15, quad = lane >> 4;
    floatx4 acc[4];
    #pragma unroll
    for (int nt = 0; nt < 4; nt++) acc[nt] = (floatx4){0.f, 0.f, 0.f, 0.f};

    const ushort* wbase = wb + ((long)(wave * 64 + mrow)) * DD + quad * 8;
    #pragma unroll 4
    for (int kc = 0; kc < DD; kc += 32) {
        shortx8 af = *(const shortx8*)&xgl[mrow][kc + quad * 8];
        #pragma unroll
        for (int nt = 0; nt < 4; nt++) {
            shortx8 bf = *(const shortx8*)(wbase + nt * 16 * DD + kc);
            acc[nt] = __builtin_amdgcn_mfma_f32_16x16x32_bf16(af, bf, acc[nt], 0, 0, 0);
        }
    }

    #pragma unroll
    for (int nt = 0; nt < 4; nt++) {
        int d = wave * 64 + nt * 16 + mrow;
        float s = sv[d], tt = tv[d];
        #pragma unroll
        for (int v = 0; v < 4; v++) {
            int m = quad * 4 + v;
            float val = fmaxf(acc[nt][v] * s + tt, 0.f);
            if (m < NP) {
                if (LAYER == 1) y1l[m][d] = val;
                else outp[((long)(b * NP + m) * TT + (TT - 1)) * DD + d] = val;
            }
        }
    }
}

// ---------------------------------------------------------------------------
// main: blocks [0,256) full per-batch STGCN chain (writes t==19 rows of out);
//       blocks [256,256+NCPY): each WAVE one-shot-copies 4 non-slice rows.
//       Non-slice row j in [0,58368) -> memory row r=(j/19)*20+j%19 (skips
//       t==19). Wave-uniform row math: zero divergence; lanes copy consecutive
//       float4 (coalesced); 8 loads in flight before any store (MLP).
// ---------------------------------------------------------------------------
__global__ __launch_bounds__(512, 4) void k_main(
    const float* __restrict__ pf, const float* __restrict__ bboxes,
    const ushort* __restrict__ wb1, const ushort* __restrict__ wb2,
    const float* __restrict__ s1, const float* __restrict__ t1,
    const float* __restrict__ s2, const float* __restrict__ t2,
    float* __restrict__ out,
    const float4* __restrict__ csrc, float4* __restrict__ cdst) {
    int bid = blockIdx.x, t = threadIdx.x;
    int lane = t & 63, wave = t >> 6;

    if (bid >= BB) {
        int u = (bid - BB) * 8 + wave;  // [0, 14592)
        int j0 = u * 4;
        int base[4];
        #pragma unroll
        for (int i = 0; i < 4; i++) {
            int j = j0 + i;
            int grp = j / 19;                      // magic-mul, wave-uniform
            int r = grp * 20 + (j - grp * 19);     // skips r%20==19
            base[i] = (r << 7) + lane;             // 128 float4 per row
        }
        float4 v[8];
        #pragma unroll
        for (int i = 0; i < 4; i++) {
            v[2 * i]     = csrc[base[i]];
            v[2 * i + 1] = csrc[base[i] + 64];
        }
        #pragma unroll
        for (int i = 0; i < 4; i++) {
            cdst[base[i]]      = v[2 * i];
            cdst[base[i] + 64] = v[2 * i + 1];
        }
        return;
    }

    __shared__ float cx[NP], cy[NP], Ash[NP][NP], rinv[NP], at[NP][NP];
    __shared__ __align__(16) ushort xgl[16][APITCH];  // bf16 A-tile (rows 12..15 zero)
    __shared__ float y1l[NP][DD];                     // fp32 layer-1 output

    int b = bid;

    // ---- adjacency ----
    if (t < NP) {
        const float* p = bboxes + (b * NP + t) * 4;
        cx[t] = p[0] + 0.5f * p[2];
        cy[t] = p[1] + 0.5f * p[3];
    }
    // zero pad rows 12..15 of xgl (MFMA reads them; must be 0)
    {
        uint* xz = (uint*)&xgl[NP][0];
        for (int i = t; i < 4 * APITCH / 2; i += 512) xz[i] = 0;
    }
    __syncthreads();
    if (t < NP * NP) {
        int n = t / NP, k = t % NP;
        float dx = cx[n] - cx[k], dy = cy[n] - cy[k];
        Ash[n][k] = (dx * dx + dy * dy < THR2) ? 1.f : 0.f;
    }
    __syncthreads();
    if (t < NP) {
        float s = 0.f;
        #pragma unroll
        for (int k = 0; k < NP; k++) s += Ash[t][k];
        rinv[t] = 1.f / (s + EPS_A);
    }
    __syncthreads();
    if (t < NP * NP) {
        int j = t / NP, n = t % NP;
        at[j][n] = Ash[n][j] * rinv[n];
    }
    __syncthreads();

    // ---- mix1: pf last slice -> xgl (bf16) ----
    for (int c = t; c < DD; c += 512) {
        float xv[NP];
        #pragma unroll
        for (int n = 0; n < NP; n++)
            xv[n] = pf[((long)((b * NP + n) * TT + TT - 1)) * DD + c];
        #pragma unroll
        for (int j = 0; j < NP; j++) {
            float a = 0.f;
            #pragma unroll
            for (int n = 0; n < NP; n++) a += at[j][n] * xv[n];
            xgl[j][c] = f2bf(a);
        }
    }
    __syncthreads();

    // ---- layer 1 GEMM + BN + relu -> y1l ----
    gemm8w<1>(wave, lane, b, xgl, y1l, wb1, s1, t1, nullptr);
    __syncthreads();  // y1l written; xgl reads done

    // ---- mix2: y1l -> xgl (bf16) ----
    for (int c = t; c < DD; c += 512) {
        float xv[NP];
        #pragma unroll
        for (int n = 0; n < NP; n++) xv[n] = y1l[n][c];
        #pragma unroll
        for (int j = 0; j < NP; j++) {
            float a = 0.f;
            #pragma unroll
            for (int n = 0; n < NP; n++) a += at[j][n] * xv[n];
            xgl[j][c] = f2bf(a);
        }
    }
    __syncthreads();

    // ---- layer 2 GEMM + BN + relu -> out slice rows ----
    gemm8w<2>(wave, lane, b, xgl, y1l, wb2, s2, t2, out);
}

// ---------------------------------------------------------------------------
extern "C" void kernel_launch(void* const* d_in, const int* in_sizes, int n_in,
                              void* d_out, int out_size, void* d_ws, size_t ws_size,
                              hipStream_t stream) {
    const float* pf = (const float*)d_in[0];
    const float* bboxes = (const float*)d_in[1];
    const float* W1 = (const float*)d_in[2];
    const float* b1 = (const float*)d_in[3];
    const float* g1 = (const float*)d_in[4];
    const float* beta1 = (const float*)d_in[5];
    const float* m1 = (const float*)d_in[6];
    const float* v1 = (const float*)d_in[7];
    const float* W2 = (const float*)d_in[8];
    const float* b2 = (const float*)d_in[9];
    const float* g2 = (const float*)d_in[10];
    const float* beta2 = (const float*)d_in[11];
    const float* m2 = (const float*)d_in[12];
    const float* v2 = (const float*)d_in[13];
    float* out = (float*)d_out;

    float* ws = (float*)d_ws;
    float* s1 = ws;
    float* t1v = ws + 512;
    float* s2 = ws + 1024;
    float* t2v = ws + 1536;
    ushort* wb1 = (ushort*)(ws + 2048);   // 262144 ushorts
    ushort* wb2 = wb1 + 262144;           // 262144 ushorts

    const float4* csrc = (const float4*)pf;
    float4* cdst = (float4*)out;

    k_prep<<<257, 256, 0, stream>>>(W1, W2, b1, g1, beta1, m1, v1,
                                    b2, g2, beta2, m2, v2,
                                    s1, t1v, s2, t2v, wb1, wb2);
    k_main<<<BB + NCPY, 512, 0, stream>>>(pf, bboxes, wb1, wb2,
                                          s1, t1v, s2, t2v, out, csrc, cdst);
}